// Round 1
// baseline (503.361 us; speedup 1.0000x reference)
//
#include <hip/hip_runtime.h>
#include <hip/hip_bf16.h>
#include <math.h>

#define NTOK 8192
#define HD   1024
#define FFND 2048
#define NE   64
#define MTOT 16384   // NTOK * TOPK
#define PER_E 256    // MTOT / NE

typedef __attribute__((ext_vector_type(8))) short bh8;
typedef __attribute__((ext_vector_type(4))) float f4;
typedef unsigned short u16;
typedef unsigned int   u32;

__device__ __forceinline__ u16 f2bf(float f) {
  union { float f; u32 u; } x; x.f = f;
  u32 r = x.u + 0x7fffu + ((x.u >> 16) & 1u);   // round-nearest-even
  return (u16)(r >> 16);
}

// slot -> source token map. scatter_index flat: sidx[t*2+k] = slot.
__global__ void k_build_s2t(const int* __restrict__ sidx, int* __restrict__ s2t) {
  int i = blockIdx.x * 256 + threadIdx.x;   // i in [0, MTOT)
  s2t[sidx[i]] = i >> 1;
}

// Gather + f32->bf16 convert: X[slot][h] = bf16(inputs[s2t[slot]][h])
__global__ void k_gather_x(const float* __restrict__ inp, const int* __restrict__ s2t,
                           u16* __restrict__ X) {
  int idx = blockIdx.x * 256 + threadIdx.x;   // MTOT*HD/8 threads
  int slot = idx >> 7;                        // HD/8 = 128 chunks per row
  int c    = idx & 127;
  const float* src = inp + (size_t)s2t[slot] * HD + c * 8;
  float v[8];
  *(f4*)(v)     = *(const f4*)(src);
  *(f4*)(v + 4) = *(const f4*)(src + 4);
  u16 o[8];
  #pragma unroll
  for (int j = 0; j < 8; ++j) o[j] = f2bf(v[j]);
  *(uint4*)(X + (size_t)slot * HD + c * 8) = *(uint4*)o;
}

// Grouped GEMM: C[row0+.., n0+..] = A[row][k] * B[e][k][n]
// A: bf16 expert-sorted [MTOT][K]. B: f32 [NE][K][N] (convert on stage).
// GELU=true: write bf16 act.  GELU=false: atomicAdd f32 into out[token][col].
template<int K, int N, bool GELU>
__global__ __launch_bounds__(512)
void moe_gemm(const u16* __restrict__ Abf, const float* __restrict__ Bf,
              u16* __restrict__ actout, float* __restrict__ redout,
              const int* __restrict__ s2t)
{
  constexpr int BM = 256, BN = 128, BK = 64;
  __shared__ char lds[BM * 128 + BN * 128];   // 48 KB: As rows 128B, Bs rows 128B
  char* As = lds;               // As[r]: 64 bf16, byte (r*128 + (kb ^ ((r&7)<<4)))
  char* Bs = lds + BM * 128;    // Bs[n]: 64 bf16 (transposed W tile)

  const int e    = blockIdx.y;
  const int n0   = blockIdx.x * BN;
  const int row0 = e * PER_E;
  const int tid  = threadIdx.x;
  const int lane = tid & 63, wid = tid >> 6;
  const int wr   = wid >> 1, wc = wid & 1;    // 4x2 waves of 64x64

  const u16*   Arow = Abf + (size_t)row0 * K;
  const float* Bsrc = Bf + (size_t)e * K * N + n0;

  f4 acc[4][4] = {};

  for (int k0 = 0; k0 < K; k0 += BK) {
    // ---- stage A: 256x64 bf16 = 2048 16B-chunks, 4 per thread ----
    #pragma unroll
    for (int i = 0; i < 4; ++i) {
      int c = i * 512 + tid;
      int r = c >> 3, kc = c & 7;
      uint4 v = *(const uint4*)(Arow + (size_t)r * K + k0 + kc * 8);
      *(uint4*)(As + r * 128 + ((kc * 16) ^ ((r & 7) << 4))) = v;
    }
    // ---- stage B: 64x128 f32 -> bf16 transposed Bs[n][k], 2 chunks/thread ----
    #pragma unroll
    for (int i = 0; i < 2; ++i) {
      int c = i * 512 + tid;
      int n = c & 127, kc = c >> 7;
      const float* p = Bsrc + (size_t)(k0 + kc * 8) * N + n;
      u16 tmp[8];
      #pragma unroll
      for (int j = 0; j < 8; ++j) tmp[j] = f2bf(p[(size_t)j * N]);
      *(uint4*)(Bs + n * 128 + ((kc * 16) ^ ((n & 7) << 4))) = *(uint4*)tmp;
    }
    __syncthreads();
    // ---- compute: 2 kk-halves x 4x4 MFMA 16x16x32 ----
    #pragma unroll
    for (int kk = 0; kk < 2; ++kk) {
      int kByte = kk * 64 + ((lane >> 4) << 4);
      bh8 a[4], b[4];
      #pragma unroll
      for (int m = 0; m < 4; ++m) {
        int r = wr * 64 + m * 16 + (lane & 15);
        a[m] = *(bh8*)(As + r * 128 + (kByte ^ ((r & 7) << 4)));
      }
      #pragma unroll
      for (int n = 0; n < 4; ++n) {
        int r = wc * 64 + n * 16 + (lane & 15);
        b[n] = *(bh8*)(Bs + r * 128 + (kByte ^ ((r & 7) << 4)));
      }
      #pragma unroll
      for (int m = 0; m < 4; ++m)
        #pragma unroll
        for (int n = 0; n < 4; ++n)
          acc[m][n] = __builtin_amdgcn_mfma_f32_16x16x32_bf16(a[m], b[n], acc[m][n], 0, 0, 0);
    }
    __syncthreads();
  }

  // ---- epilogue ----
  // C layout (m89): col = lane&15, row = (lane>>4)*4 + j
  #pragma unroll
  for (int m = 0; m < 4; ++m) {
    #pragma unroll
    for (int n = 0; n < 4; ++n) {
      int rowb = wr * 64 + m * 16 + ((lane >> 4) << 2);
      int col  = n0 + wc * 64 + n * 16 + (lane & 15);
      #pragma unroll
      for (int j = 0; j < 4; ++j) {
        float x = acc[m][n][j];
        if (GELU) {
          float g = 0.5f * x * (1.0f + erff(x * 0.70710678118f));
          actout[(size_t)(row0 + rowb + j) * N + col] = f2bf(g);
        } else {
          int token = s2t[row0 + rowb + j];
          atomicAdd(redout + (size_t)token * HD + col, x);
        }
      }
    }
  }
}

extern "C" void kernel_launch(void* const* d_in, const int* in_sizes, int n_in,
                              void* d_out, int out_size, void* d_ws, size_t ws_size,
                              hipStream_t stream) {
  const float* inp  = (const float*)d_in[0];
  const float* w1   = (const float*)d_in[1];
  const float* w2   = (const float*)d_in[2];
  const int*   sidx = (const int*)d_in[3];
  float* out = (float*)d_out;

  char* ws  = (char*)d_ws;
  int*  s2t = (int*)ws;                                   // 64 KB
  u16*  X   = (u16*)(ws + (1 << 20));                     // 32 MB bf16 [MTOT][HD]
  u16*  act = (u16*)(ws + (1 << 20) + (32u << 20));       // 64 MB bf16 [MTOT][FFND]

  hipMemsetAsync(d_out, 0, (size_t)out_size * sizeof(float), stream);
  k_build_s2t<<<MTOT / 256, 256, 0, stream>>>(sidx, s2t);
  k_gather_x<<<(MTOT * (HD / 8)) / 256, 256, 0, stream>>>(inp, s2t, X);
  moe_gemm<HD, FFND, true><<<dim3(FFND / 128, NE), 512, 0, stream>>>(X, w1, act, nullptr, nullptr);
  moe_gemm<FFND, HD, false><<<dim3(HD / 128, NE), 512, 0, stream>>>(act, w2, nullptr, out, s2t);
}

// Round 2
// 485.539 us; speedup vs baseline: 1.0367x; 1.0367x over previous
//
#include <hip/hip_runtime.h>
#include <hip/hip_bf16.h>
#include <math.h>

#define NTOK 8192
#define HD   1024
#define FFND 2048
#define NE   64
#define MTOT 16384   // NTOK * TOPK
#define PER_E 256    // MTOT / NE

typedef __attribute__((ext_vector_type(8))) short bh8;
typedef __attribute__((ext_vector_type(4))) float f4;
typedef unsigned short u16;
typedef unsigned int   u32;

__device__ __forceinline__ u16 f2bf(float f) {
  union { float f; u32 u; } x; x.f = f;
  u32 r = x.u + 0x7fffu + ((x.u >> 16) & 1u);   // round-nearest-even
  return (u16)(r >> 16);
}

// slot -> source token map. scatter_index flat: sidx[t*2+k] = slot.
__global__ void k_build_s2t(const int* __restrict__ sidx, int* __restrict__ s2t) {
  int i = blockIdx.x * 256 + threadIdx.x;   // i in [0, MTOT)
  s2t[sidx[i]] = i >> 1;
}

// Gather + f32->bf16 convert: X[slot][h] = bf16(inputs[s2t[slot]][h])
__global__ void k_gather_x(const float* __restrict__ inp, const int* __restrict__ s2t,
                           u16* __restrict__ X) {
  int idx = blockIdx.x * 256 + threadIdx.x;   // MTOT*HD/8 threads
  int slot = idx >> 7;                        // HD/8 = 128 chunks per row
  int c    = idx & 127;
  const float* src = inp + (size_t)s2t[slot] * HD + c * 8;
  float v[8];
  *(f4*)(v)     = *(const f4*)(src);
  *(f4*)(v + 4) = *(const f4*)(src + 4);
  u16 o[8];
  #pragma unroll
  for (int j = 0; j < 8; ++j) o[j] = f2bf(v[j]);
  *(uint4*)(X + (size_t)slot * HD + c * 8) = *(uint4*)o;
}

// Grouped GEMM: C[row0+.., n0+..] = A[row][k] * B[e][k][n]
// A: bf16 expert-sorted [MTOT][K]. B: f32 [NE][K][N] (convert on stage).
// GELU=true: write bf16 act.  GELU=false: write f32 partials to redout[row][col].
template<int K, int N, bool GELU>
__global__ __launch_bounds__(512)
void moe_gemm(const u16* __restrict__ Abf, const float* __restrict__ Bf,
              u16* __restrict__ actout, float* __restrict__ redout)
{
  constexpr int BM = 256, BN = 128, BK = 64;
  __shared__ char lds[BM * 128 + BN * 128];   // 48 KB: As rows 128B, Bs rows 128B
  char* As = lds;               // As[r]: 64 bf16, byte (r*128 + (kb ^ ((r&7)<<4)))
  char* Bs = lds + BM * 128;    // Bs[n]: 64 bf16 (transposed W tile)

  const int e    = blockIdx.y;
  const int n0   = blockIdx.x * BN;
  const int row0 = e * PER_E;
  const int tid  = threadIdx.x;
  const int lane = tid & 63, wid = tid >> 6;
  const int wr   = wid >> 1, wc = wid & 1;    // 4x2 waves of 64x64

  const u16*   Arow = Abf + (size_t)row0 * K;
  const float* Bsrc = Bf + (size_t)e * K * N + n0;

  f4 acc[4][4] = {};

  for (int k0 = 0; k0 < K; k0 += BK) {
    // ---- stage A: 256x64 bf16 = 2048 16B-chunks, 4 per thread ----
    #pragma unroll
    for (int i = 0; i < 4; ++i) {
      int c = i * 512 + tid;
      int r = c >> 3, kc = c & 7;
      uint4 v = *(const uint4*)(Arow + (size_t)r * K + k0 + kc * 8);
      *(uint4*)(As + r * 128 + ((kc * 16) ^ ((r & 7) << 4))) = v;
    }
    // ---- stage B: 64x128 f32 -> bf16 transposed Bs[n][k], 2 chunks/thread ----
    #pragma unroll
    for (int i = 0; i < 2; ++i) {
      int c = i * 512 + tid;
      int n = c & 127, kc = c >> 7;
      const float* p = Bsrc + (size_t)(k0 + kc * 8) * N + n;
      u16 tmp[8];
      #pragma unroll
      for (int j = 0; j < 8; ++j) tmp[j] = f2bf(p[(size_t)j * N]);
      *(uint4*)(Bs + n * 128 + ((kc * 16) ^ ((n & 7) << 4))) = *(uint4*)tmp;
    }
    __syncthreads();
    // ---- compute: 2 kk-halves x 4x4 MFMA 16x16x32 ----
    #pragma unroll
    for (int kk = 0; kk < 2; ++kk) {
      int kByte = kk * 64 + ((lane >> 4) << 4);
      bh8 a[4], b[4];
      #pragma unroll
      for (int m = 0; m < 4; ++m) {
        int r = wr * 64 + m * 16 + (lane & 15);
        a[m] = *(bh8*)(As + r * 128 + (kByte ^ ((r & 7) << 4)));
      }
      #pragma unroll
      for (int n = 0; n < 4; ++n) {
        int r = wc * 64 + n * 16 + (lane & 15);
        b[n] = *(bh8*)(Bs + r * 128 + (kByte ^ ((r & 7) << 4)));
      }
      #pragma unroll
      for (int m = 0; m < 4; ++m)
        #pragma unroll
        for (int n = 0; n < 4; ++n)
          acc[m][n] = __builtin_amdgcn_mfma_f32_16x16x32_bf16(a[m], b[n], acc[m][n], 0, 0, 0);
    }
    __syncthreads();
  }

  // ---- epilogue ----
  // C layout (m89): col = lane&15, row = (lane>>4)*4 + j
  #pragma unroll
  for (int m = 0; m < 4; ++m) {
    #pragma unroll
    for (int n = 0; n < 4; ++n) {
      int rowb = wr * 64 + m * 16 + ((lane >> 4) << 2);
      int col  = n0 + wc * 64 + n * 16 + (lane & 15);
      #pragma unroll
      for (int j = 0; j < 4; ++j) {
        float x = acc[m][n][j];
        if (GELU) {
          float g = 0.5f * x * (1.0f + erff(x * 0.70710678118f));
          actout[(size_t)(row0 + rowb + j) * N + col] = f2bf(g);
        } else {
          redout[(size_t)(row0 + rowb + j) * N + col] = x;
        }
      }
    }
  }
}

// out[t][:] = h2[sidx[2t]][:] + h2[sidx[2t+1]][:]   (fully overwrites d_out)
__global__ void k_reduce(const float* __restrict__ h2, const int* __restrict__ sidx,
                         float* __restrict__ out) {
  int t = blockIdx.x;
  int c = threadIdx.x;                        // 256 threads x f4 = 1024 floats
  const f4* r0 = (const f4*)(h2 + (size_t)sidx[2 * t] * HD);
  const f4* r1 = (const f4*)(h2 + (size_t)sidx[2 * t + 1] * HD);
  ((f4*)(out + (size_t)t * HD))[c] = r0[c] + r1[c];
}

extern "C" void kernel_launch(void* const* d_in, const int* in_sizes, int n_in,
                              void* d_out, int out_size, void* d_ws, size_t ws_size,
                              hipStream_t stream) {
  const float* inp  = (const float*)d_in[0];
  const float* w1   = (const float*)d_in[1];
  const float* w2   = (const float*)d_in[2];
  const int*   sidx = (const int*)d_in[3];
  float* out = (float*)d_out;

  char* ws   = (char*)d_ws;
  int*   s2t = (int*)ws;                                          // 64 KB
  u16*   X   = (u16*)(ws + (1 << 20));                            // 32 MB bf16 [MTOT][HD]
  u16*   act = (u16*)(ws + (1 << 20) + (32u << 20));              // 64 MB bf16 [MTOT][FFND]
  float* h2  = (float*)(ws + (1 << 20) + (96u << 20));            // 64 MB f32 [MTOT][HD]

  k_build_s2t<<<MTOT / 256, 256, 0, stream>>>(sidx, s2t);
  k_gather_x<<<(MTOT * (HD / 8)) / 256, 256, 0, stream>>>(inp, s2t, X);
  moe_gemm<HD, FFND, true><<<dim3(FFND / 128, NE), 512, 0, stream>>>(X, w1, act, nullptr);
  moe_gemm<FFND, HD, false><<<dim3(HD / 128, NE), 512, 0, stream>>>(act, w2, nullptr, h2);
  k_reduce<<<NTOK, 256, 0, stream>>>(h2, sidx, out);
}

// Round 3
// 327.230 us; speedup vs baseline: 1.5382x; 1.4838x over previous
//
#include <hip/hip_runtime.h>
#include <hip/hip_bf16.h>
#include <math.h>

#define NTOK 8192
#define HD   1024
#define FFND 2048
#define NE   64
#define MTOT 16384   // NTOK * TOPK
#define PER_E 256    // MTOT / NE

typedef __attribute__((ext_vector_type(8))) short bh8;
typedef __attribute__((ext_vector_type(4))) float f4;
typedef unsigned short u16;
typedef unsigned int   u32;

__device__ __forceinline__ u16 f2bf(float f) {
  union { float f; u32 u; } x; x.f = f;
  u32 r = x.u + 0x7fffu + ((x.u >> 16) & 1u);   // round-nearest-even
  return (u16)(r >> 16);
}

__device__ __forceinline__ u32 pk2(float lo, float hi) {
  __hip_bfloat162 h = __float22bfloat162_rn(make_float2(lo, hi));
  union { __hip_bfloat162 h; u32 u; } c; c.h = h;
  return c.u;
}

// slot -> source token map. scatter_index flat: sidx[t*2+k] = slot.
__global__ void k_build_s2t(const int* __restrict__ sidx, int* __restrict__ s2t) {
  int i = blockIdx.x * 256 + threadIdx.x;   // i in [0, MTOT)
  s2t[sidx[i]] = i >> 1;
}

// Gather + f32->bf16 convert: X[slot][h] = bf16(inputs[s2t[slot]][h])
__global__ void k_gather_x(const float* __restrict__ inp, const int* __restrict__ s2t,
                           u16* __restrict__ X) {
  int idx = blockIdx.x * 256 + threadIdx.x;   // MTOT*HD/8 threads
  int slot = idx >> 7;                        // HD/8 = 128 chunks per row
  int c    = idx & 127;
  const float* src = inp + (size_t)s2t[slot] * HD + c * 8;
  float v[8];
  *(f4*)(v)     = *(const f4*)(src);
  *(f4*)(v + 4) = *(const f4*)(src + 4);
  u32 o[4];
  #pragma unroll
  for (int j = 0; j < 4; ++j) o[j] = pk2(v[2 * j], v[2 * j + 1]);
  *(uint4*)(X + (size_t)slot * HD + c * 8) = *(uint4*)o;
}

// Grouped GEMM: C[row0+.., n0+..] = A[row][k] * B[e][k][n]
// A: bf16 expert-sorted [MTOT][K], staged via global_load_lds (pre-swizzled src).
// B: f32 [NE][K][N], reg-staged with cvt_pk convert, k-transposed into LDS.
// GELU=true: write bf16 act.  GELU=false: write f32 partials to redout[row][col].
template<int K, int N, bool GELU>
__global__ __launch_bounds__(512, 4)
void moe_gemm(const u16* __restrict__ Abf, const float* __restrict__ Bf,
              u16* __restrict__ actout, float* __restrict__ redout)
{
  constexpr int BM = 256, BN = 128, BK = 64;
  constexpr int NB = N / BN;                  // n0-blocks per expert
  __shared__ __align__(16) char lds[BM * 128 + BN * 128];  // 48 KB
  char* As = lds;               // As[r]: 64 bf16; chunk j holds A[r][chunk j^(r&7)]
  char* Bs = lds + BM * 128;    // Bs[n]: 64 bf16 (k-contig), 16B-chunk XOR (n&7)

  // XCD-chunked swizzle: dispatch d -> xcd d%8 (heuristic). Give each XCD a
  // contiguous run of 8 experts so all NB blocks of an expert share one L2.
  const int d = blockIdx.y * NB + blockIdx.x;
  const int x = d & 7, j = d >> 3;
  const int e  = x * 8 + (j & 7);
  const int n0 = (j >> 3) * BN;
  const int row0 = e * PER_E;
  const int tid  = threadIdx.x;
  const int lane = tid & 63, wid = tid >> 6;
  const int wr   = wid >> 1, wc = wid & 1;    // 4x2 waves of 64x64

  const u16*   Arow = Abf + (size_t)row0 * K;
  const float* Bsrc = Bf + (size_t)e * K * N + n0;

  f4 acc[4][4] = {};

  for (int k0 = 0; k0 < K; k0 += BK) {
    // ---- stage A: 256x64 bf16 via global_load_lds, dest linear, src XOR'd ----
    #pragma unroll
    for (int i = 0; i < 4; ++i) {
      int c = i * 512 + tid;
      int r = c >> 3, kc = c & 7;
      int kswz = kc ^ (r & 7);
      __builtin_amdgcn_global_load_lds(
          (const void*)(Arow + (size_t)r * K + k0 + kswz * 8),
          (void*)(As + c * 16), 16, 0, 0);
    }
    // ---- stage B: 64x128 f32 -> bf16 transposed Bs[n][k] via cvt_pk pairs ----
    #pragma unroll
    for (int i = 0; i < 2; ++i) {
      int c = i * 512 + tid;
      int n = c & 127, kc = c >> 7;
      const float* p = Bsrc + (size_t)(k0 + kc * 8) * N + n;
      u32 q[4];
      #pragma unroll
      for (int jj = 0; jj < 4; ++jj)
        q[jj] = pk2(p[(size_t)(2 * jj) * N], p[(size_t)(2 * jj + 1) * N]);
      *(uint4*)(Bs + n * 128 + ((kc * 16) ^ ((n & 7) << 4))) = *(uint4*)q;
    }
    __syncthreads();
    // ---- compute: 2 kk-halves x 4x4 MFMA 16x16x32 ----
    #pragma unroll
    for (int kk = 0; kk < 2; ++kk) {
      int kByte = kk * 64 + ((lane >> 4) << 4);
      bh8 a[4], b[4];
      #pragma unroll
      for (int m = 0; m < 4; ++m) {
        int r = wr * 64 + m * 16 + (lane & 15);
        a[m] = *(bh8*)(As + r * 128 + (kByte ^ ((r & 7) << 4)));
      }
      #pragma unroll
      for (int n = 0; n < 4; ++n) {
        int r = wc * 64 + n * 16 + (lane & 15);
        b[n] = *(bh8*)(Bs + r * 128 + (kByte ^ ((r & 7) << 4)));
      }
      #pragma unroll
      for (int m = 0; m < 4; ++m)
        #pragma unroll
        for (int n = 0; n < 4; ++n)
          acc[m][n] = __builtin_amdgcn_mfma_f32_16x16x32_bf16(a[m], b[n], acc[m][n], 0, 0, 0);
    }
    __syncthreads();
  }

  // ---- epilogue ----
  // C layout (m89): col = lane&15, row = (lane>>4)*4 + j
  #pragma unroll
  for (int m = 0; m < 4; ++m) {
    #pragma unroll
    for (int n = 0; n < 4; ++n) {
      int rowb = wr * 64 + m * 16 + ((lane >> 4) << 2);
      int col  = n0 + wc * 64 + n * 16 + (lane & 15);
      #pragma unroll
      for (int jj = 0; jj < 4; ++jj) {
        float xv = acc[m][n][jj];
        if (GELU) {
          // tanh-form GELU: y/(1+exp(-2u)), u = 0.79788456(y + 0.044715 y^3)
          float y = fminf(fmaxf(xv, -8.f), 8.f);
          float u = 0.7978845608f * (y + 0.044715f * y * y * y);
          float t = __expf(-2.f * u);
          float g = __fdividef(y, 1.f + t);
          actout[(size_t)(row0 + rowb + jj) * N + col] = f2bf(g);
        } else {
          redout[(size_t)(row0 + rowb + jj) * N + col] = xv;
        }
      }
    }
  }
}

// out[t][:] = h2[sidx[2t]][:] + h2[sidx[2t+1]][:]   (fully overwrites d_out)
__global__ void k_reduce(const float* __restrict__ h2, const int* __restrict__ sidx,
                         float* __restrict__ out) {
  int t = blockIdx.x;
  int c = threadIdx.x;                        // 256 threads x f4 = 1024 floats
  const f4* r0 = (const f4*)(h2 + (size_t)sidx[2 * t] * HD);
  const f4* r1 = (const f4*)(h2 + (size_t)sidx[2 * t + 1] * HD);
  ((f4*)(out + (size_t)t * HD))[c] = r0[c] + r1[c];
}

extern "C" void kernel_launch(void* const* d_in, const int* in_sizes, int n_in,
                              void* d_out, int out_size, void* d_ws, size_t ws_size,
                              hipStream_t stream) {
  const float* inp  = (const float*)d_in[0];
  const float* w1   = (const float*)d_in[1];
  const float* w2   = (const float*)d_in[2];
  const int*   sidx = (const int*)d_in[3];
  float* out = (float*)d_out;

  char* ws   = (char*)d_ws;
  int*   s2t = (int*)ws;                                          // 64 KB
  u16*   X   = (u16*)(ws + (1 << 20));                            // 32 MB bf16 [MTOT][HD]
  u16*   act = (u16*)(ws + (1 << 20) + (32u << 20));              // 64 MB bf16 [MTOT][FFND]
  float* h2  = (float*)(ws + (1 << 20) + (96u << 20));            // 64 MB f32 [MTOT][HD]

  k_build_s2t<<<MTOT / 256, 256, 0, stream>>>(sidx, s2t);
  k_gather_x<<<(MTOT * (HD / 8)) / 256, 256, 0, stream>>>(inp, s2t, X);
  moe_gemm<HD, FFND, true><<<dim3(FFND / 128, NE), 512, 0, stream>>>(X, w1, act, nullptr);
  moe_gemm<FFND, HD, false><<<dim3(HD / 128, NE), 512, 0, stream>>>(act, w2, nullptr, h2);
  k_reduce<<<NTOK, 256, 0, stream>>>(h2, sidx, out);
}

// Round 4
// 315.749 us; speedup vs baseline: 1.5942x; 1.0364x over previous
//
#include <hip/hip_runtime.h>
#include <hip/hip_bf16.h>
#include <math.h>

#define NTOK 8192
#define HD   1024
#define FFND 2048
#define NE   64
#define MTOT 16384   // NTOK * TOPK
#define PER_E 256    // MTOT / NE

typedef __attribute__((ext_vector_type(8))) short bh8;
typedef __attribute__((ext_vector_type(4))) float f4;
typedef unsigned short u16;
typedef unsigned int   u32;

__device__ __forceinline__ u16 f2bf(float f) {
  union { float f; u32 u; } x; x.f = f;
  u32 r = x.u + 0x7fffu + ((x.u >> 16) & 1u);   // round-nearest-even
  return (u16)(r >> 16);
}

__device__ __forceinline__ u32 pk2(float lo, float hi) {
  __hip_bfloat162 h = __float22bfloat162_rn(make_float2(lo, hi));
  union { __hip_bfloat162 h; u32 u; } c; c.h = h;
  return c.u;
}

// slot -> source token map. scatter_index flat: sidx[t*2+k] = slot.
__global__ void k_build_s2t(const int* __restrict__ sidx, int* __restrict__ s2t) {
  int i = blockIdx.x * 256 + threadIdx.x;   // i in [0, MTOT)
  s2t[sidx[i]] = i >> 1;
}

// Gather + f32->bf16 convert: X[slot][h] = bf16(inputs[s2t[slot]][h])
__global__ void k_gather_x(const float* __restrict__ inp, const int* __restrict__ s2t,
                           u16* __restrict__ X) {
  int idx = blockIdx.x * 256 + threadIdx.x;   // MTOT*HD/8 threads
  int slot = idx >> 7;                        // HD/8 = 128 chunks per row
  int c    = idx & 127;
  const float* src = inp + (size_t)s2t[slot] * HD + c * 8;
  float v[8];
  *(f4*)(v)     = *(const f4*)(src);
  *(f4*)(v + 4) = *(const f4*)(src + 4);
  u32 o[4];
  #pragma unroll
  for (int j = 0; j < 4; ++j) o[j] = pk2(v[2 * j], v[2 * j + 1]);
  *(uint4*)(X + (size_t)slot * HD + c * 8) = *(uint4*)o;
}

// Grouped GEMM: C[row0+.., n0+..] = A[row][k] * B[e][k][n]
// A: bf16 expert-sorted [MTOT][K], staged via global_load_lds (pre-swizzled src).
// B: f32 [NE][K][N], reg-staged with cvt_pk convert, k-transposed into LDS.
// GELU=true: write bf16 act.  GELU=false: write f32 partials to redout[row][col].
template<int K, int N, bool GELU>
__global__ __launch_bounds__(512, 4)
void moe_gemm(const u16* __restrict__ Abf, const float* __restrict__ Bf,
              u16* __restrict__ actout, float* __restrict__ redout)
{
  constexpr int BM = 256, BN = 128, BK = 64;
  constexpr int NB = N / BN;                  // n0-blocks per expert
  __shared__ __align__(16) char lds[BM * 128 + BN * 128];  // 48 KB
  char* As = lds;               // As[r]: 64 bf16; chunk j holds A[r][chunk j^(r&7)]
  char* Bs = lds + BM * 128;    // Bs[n]: 64 bf16 (k-contig), 16B-chunk XOR (n&7)

  // XCD swizzle, n0 INNERMOST: dispatch d -> xcd d%8 (heuristic). XCD x owns
  // experts x*8..x*8+7; consecutive j within an expert sweep all n0-blocks,
  // so co-resident blocks share one expert's A panel (512KB-1MB << 4MB L2).
  const int d = blockIdx.y * NB + blockIdx.x;
  const int x = d & 7, j = d >> 3;
  const int e  = x * (NE / 8) + j / NB;
  const int n0 = (j % NB) * BN;
  const int row0 = e * PER_E;
  const int tid  = threadIdx.x;
  const int lane = tid & 63, wid = tid >> 6;
  const int wr   = wid >> 1, wc = wid & 1;    // 4x2 waves of 64x64

  const u16*   Arow = Abf + (size_t)row0 * K;
  const float* Bsrc = Bf + (size_t)e * K * N + n0;

  f4 acc[4][4] = {};

  for (int k0 = 0; k0 < K; k0 += BK) {
    // ---- stage A: 256x64 bf16 via global_load_lds, dest linear, src XOR'd ----
    #pragma unroll
    for (int i = 0; i < 4; ++i) {
      int c = i * 512 + tid;
      int r = c >> 3, kc = c & 7;
      int kswz = kc ^ (r & 7);
      __builtin_amdgcn_global_load_lds(
          (const void*)(Arow + (size_t)r * K + k0 + kswz * 8),
          (void*)(As + c * 16), 16, 0, 0);
    }
    // ---- stage B: 64x128 f32 -> bf16 transposed Bs[n][k] via cvt_pk pairs ----
    #pragma unroll
    for (int i = 0; i < 2; ++i) {
      int c = i * 512 + tid;
      int n = c & 127, kc = c >> 7;
      const float* p = Bsrc + (size_t)(k0 + kc * 8) * N + n;
      u32 q[4];
      #pragma unroll
      for (int jj = 0; jj < 4; ++jj)
        q[jj] = pk2(p[(size_t)(2 * jj) * N], p[(size_t)(2 * jj + 1) * N]);
      *(uint4*)(Bs + n * 128 + ((kc * 16) ^ ((n & 7) << 4))) = *(uint4*)q;
    }
    __syncthreads();
    // ---- compute: 2 kk-halves x 4x4 MFMA 16x16x32 ----
    #pragma unroll
    for (int kk = 0; kk < 2; ++kk) {
      int kByte = kk * 64 + ((lane >> 4) << 4);
      bh8 a[4], b[4];
      #pragma unroll
      for (int m = 0; m < 4; ++m) {
        int r = wr * 64 + m * 16 + (lane & 15);
        a[m] = *(bh8*)(As + r * 128 + (kByte ^ ((r & 7) << 4)));
      }
      #pragma unroll
      for (int n = 0; n < 4; ++n) {
        int r = wc * 64 + n * 16 + (lane & 15);
        b[n] = *(bh8*)(Bs + r * 128 + (kByte ^ ((r & 7) << 4)));
      }
      #pragma unroll
      for (int m = 0; m < 4; ++m)
        #pragma unroll
        for (int n = 0; n < 4; ++n)
          acc[m][n] = __builtin_amdgcn_mfma_f32_16x16x32_bf16(a[m], b[n], acc[m][n], 0, 0, 0);
    }
    __syncthreads();
  }

  // ---- epilogue ----
  // C layout (m89): col = lane&15, row = (lane>>4)*4 + j
  #pragma unroll
  for (int m = 0; m < 4; ++m) {
    #pragma unroll
    for (int n = 0; n < 4; ++n) {
      int rowb = wr * 64 + m * 16 + ((lane >> 4) << 2);
      int col  = n0 + wc * 64 + n * 16 + (lane & 15);
      #pragma unroll
      for (int jj = 0; jj < 4; ++jj) {
        float xv = acc[m][n][jj];
        if (GELU) {
          // tanh-form GELU: y/(1+exp(-2u)), u = 0.79788456(y + 0.044715 y^3)
          float y = fminf(fmaxf(xv, -8.f), 8.f);
          float u = 0.7978845608f * (y + 0.044715f * y * y * y);
          float t = __expf(-2.f * u);
          float g = __fdividef(y, 1.f + t);
          actout[(size_t)(row0 + rowb + jj) * N + col] = f2bf(g);
        } else {
          redout[(size_t)(row0 + rowb + jj) * N + col] = xv;
        }
      }
    }
  }
}

// out[t][:] = h2[sidx[2t]][:] + h2[sidx[2t+1]][:]   (fully overwrites d_out)
__global__ void k_reduce(const float* __restrict__ h2, const int* __restrict__ sidx,
                         float* __restrict__ out) {
  int t = blockIdx.x;
  int c = threadIdx.x;                        // 256 threads x f4 = 1024 floats
  const f4* r0 = (const f4*)(h2 + (size_t)sidx[2 * t] * HD);
  const f4* r1 = (const f4*)(h2 + (size_t)sidx[2 * t + 1] * HD);
  ((f4*)(out + (size_t)t * HD))[c] = r0[c] + r1[c];
}

extern "C" void kernel_launch(void* const* d_in, const int* in_sizes, int n_in,
                              void* d_out, int out_size, void* d_ws, size_t ws_size,
                              hipStream_t stream) {
  const float* inp  = (const float*)d_in[0];
  const float* w1   = (const float*)d_in[1];
  const float* w2   = (const float*)d_in[2];
  const int*   sidx = (const int*)d_in[3];
  float* out = (float*)d_out;

  char* ws   = (char*)d_ws;
  int*   s2t = (int*)ws;                                          // 64 KB
  u16*   X   = (u16*)(ws + (1 << 20));                            // 32 MB bf16 [MTOT][HD]
  u16*   act = (u16*)(ws + (1 << 20) + (32u << 20));              // 64 MB bf16 [MTOT][FFND]
  float* h2  = (float*)(ws + (1 << 20) + (96u << 20));            // 64 MB f32 [MTOT][HD]

  k_build_s2t<<<MTOT / 256, 256, 0, stream>>>(sidx, s2t);
  k_gather_x<<<(MTOT * (HD / 8)) / 256, 256, 0, stream>>>(inp, s2t, X);
  moe_gemm<HD, FFND, true><<<dim3(FFND / 128, NE), 512, 0, stream>>>(X, w1, act, nullptr);
  moe_gemm<FFND, HD, false><<<dim3(HD / 128, NE), 512, 0, stream>>>(act, w2, nullptr, h2);
  k_reduce<<<NTOK, 256, 0, stream>>>(h2, sidx, out);
}

// Round 6
// 308.845 us; speedup vs baseline: 1.6298x; 1.0224x over previous
//
#include <hip/hip_runtime.h>
#include <hip/hip_bf16.h>
#include <math.h>

#define NTOK 8192
#define HD   1024
#define FFND 2048
#define NE   64
#define MTOT 16384   // NTOK * TOPK
#define PER_E 256    // MTOT / NE

typedef __attribute__((ext_vector_type(8))) short bh8;
typedef __attribute__((ext_vector_type(4))) float f4;
typedef unsigned short u16;
typedef unsigned int   u32;

__device__ __forceinline__ u16 f2bf(float f) {
  union { float f; u32 u; } x; x.f = f;
  u32 r = x.u + 0x7fffu + ((x.u >> 16) & 1u);   // round-nearest-even
  return (u16)(r >> 16);
}

__device__ __forceinline__ u32 pk2(float lo, float hi) {
  __hip_bfloat162 h = __float22bfloat162_rn(make_float2(lo, hi));
  union { __hip_bfloat162 h; u32 u; } c; c.h = h;
  return c.u;
}

// slot -> source token map. scatter_index flat: sidx[t*2+k] = slot.
__global__ void k_build_s2t(const int* __restrict__ sidx, int* __restrict__ s2t) {
  int i = blockIdx.x * 256 + threadIdx.x;   // i in [0, MTOT)
  s2t[sidx[i]] = i >> 1;
}

// Gather + f32->bf16 convert: X[slot][h] = bf16(inputs[s2t[slot]][h])
__global__ void k_gather_x(const float* __restrict__ inp, const int* __restrict__ s2t,
                           u16* __restrict__ X) {
  int idx = blockIdx.x * 256 + threadIdx.x;   // MTOT*HD/8 threads
  int slot = idx >> 7;                        // HD/8 = 128 chunks per row
  int c    = idx & 127;
  const float* src = inp + (size_t)s2t[slot] * HD + c * 8;
  float v[8];
  *(f4*)(v)     = *(const f4*)(src);
  *(f4*)(v + 4) = *(const f4*)(src + 4);
  u32 o[4];
  #pragma unroll
  for (int j = 0; j < 4; ++j) o[j] = pk2(v[2 * j], v[2 * j + 1]);
  *(uint4*)(X + (size_t)slot * HD + c * 8) = *(uint4*)o;
}

// Grouped GEMM, depth-1 prefetch pipeline:
//   A: bf16 [MTOT][K] -> global_load_lds into DOUBLE-buffered As (src pre-swizzled)
//   B: f32 [NE][K][N] -> prefetch to 16 regs, cvt_pk -> single Bs after MFMA
//   one vmcnt(0)+lgkmcnt(0) drain per K-step, placed AFTER the MFMA cluster
//   (next tile's loads stay in flight through the MFMAs). Raw s_barrier.
// GELU=true: write bf16 act.  GELU=false: write f32 partials to redout.
template<int K, int N, bool GELU>
__global__ __launch_bounds__(512, 4)
void moe_gemm(const u16* __restrict__ Abf, const float* __restrict__ Bf,
              u16* __restrict__ actout, float* __restrict__ redout)
{
  constexpr int BM = 256, BN = 128, BK = 64;
  constexpr int NB = N / BN;                  // n0-blocks per expert
  constexpr int NT = K / BK;                  // K-steps
  constexpr int ABYTES = BM * 128;            // one As buffer
  __shared__ __align__(16) char lds[2 * ABYTES + BN * 128];  // 80 KB
  char* Bs = lds + 2 * ABYTES;     // Bs[n]: 64 bf16 (k-contig), chunk XOR (n&7)

  // XCD swizzle, n0 innermost: co-resident blocks on an XCD share A panels.
  const int d = blockIdx.y * NB + blockIdx.x;
  const int x = d & 7, j = d >> 3;
  const int e  = x * (NE / 8) + j / NB;
  const int n0 = (j % NB) * BN;
  const int row0 = e * PER_E;
  const int tid  = threadIdx.x;
  const int lane = tid & 63, wid = tid >> 6;
  const int wr   = wid >> 1, wc = wid & 1;    // 4x2 waves of 64x64

  const u16*   Arow = Abf + (size_t)row0 * K;
  const float* Bsrc = Bf + (size_t)e * K * N + n0;

  // A-stage: 256x64 bf16 via global_load_lds, dest linear, src chunk XOR'd
  auto stageA = [&](int buf, int k0) {
    char* dst = lds + buf * ABYTES;
    #pragma unroll
    for (int i = 0; i < 4; ++i) {
      int c = i * 512 + tid;
      int r = c >> 3, kc = c & 7;
      int kswz = kc ^ (r & 7);
      __builtin_amdgcn_global_load_lds(
          (const void*)(Arow + (size_t)r * K + k0 + kswz * 8),
          (void*)(dst + c * 16), 16, 0, 0);
    }
  };
  // B-prefetch: 16 strided f32 loads into regs
  auto loadB = [&](float* br, int k0) {
    #pragma unroll
    for (int i = 0; i < 2; ++i) {
      int c = i * 512 + tid;
      int n = c & 127, kc = c >> 7;
      const float* p = Bsrc + (size_t)(k0 + kc * 8) * N + n;
      #pragma unroll
      for (int jj = 0; jj < 8; ++jj) br[i * 8 + jj] = p[(size_t)jj * N];
    }
  };
  // B-publish: cvt_pk pairs -> Bs[n][k] (k-transposed, XOR-swizzled)
  auto writeB = [&](const float* br) {
    #pragma unroll
    for (int i = 0; i < 2; ++i) {
      int c = i * 512 + tid;
      int n = c & 127, kc = c >> 7;
      u32 q[4];
      #pragma unroll
      for (int jj = 0; jj < 4; ++jj) q[jj] = pk2(br[i * 8 + 2 * jj], br[i * 8 + 2 * jj + 1]);
      *(uint4*)(Bs + n * 128 + ((kc * 16) ^ ((n & 7) << 4))) = *(uint4*)q;
    }
  };

  f4 acc[4][4] = {};
  float breg[16];

  // ---- prologue: stage tile 0 ----
  stageA(0, 0);
  loadB(breg, 0);
  writeB(breg);                       // compiler inserts vmcnt waits for breg
  asm volatile("s_waitcnt vmcnt(0) lgkmcnt(0)" ::: "memory");
  __builtin_amdgcn_sched_barrier(0);
  __builtin_amdgcn_s_barrier();
  __builtin_amdgcn_sched_barrier(0);

  int cur = 0;
  for (int t = 0; t < NT; ++t) {
    const char* As = lds + cur * ABYTES;
    // ---- issue next tile's loads (stay in flight through the MFMAs) ----
    if (t + 1 < NT) {
      stageA(cur ^ 1, (t + 1) * BK);
      loadB(breg, (t + 1) * BK);
    }
    // ---- compute tile t: 2 kk-halves x 4x4 MFMA 16x16x32 ----
    __builtin_amdgcn_s_setprio(1);
    #pragma unroll
    for (int kk = 0; kk < 2; ++kk) {
      int kByte = kk * 64 + ((lane >> 4) << 4);
      bh8 a[4], b[4];
      #pragma unroll
      for (int m = 0; m < 4; ++m) {
        int r = wr * 64 + m * 16 + (lane & 15);
        a[m] = *(const bh8*)(As + r * 128 + (kByte ^ ((r & 7) << 4)));
      }
      #pragma unroll
      for (int n = 0; n < 4; ++n) {
        int r = wc * 64 + n * 16 + (lane & 15);
        b[n] = *(const bh8*)(Bs + r * 128 + (kByte ^ ((r & 7) << 4)));
      }
      #pragma unroll
      for (int m = 0; m < 4; ++m)
        #pragma unroll
        for (int n = 0; n < 4; ++n)
          acc[m][n] = __builtin_amdgcn_mfma_f32_16x16x32_bf16(a[m], b[n], acc[m][n], 0, 0, 0);
    }
    __builtin_amdgcn_s_setprio(0);
    // ---- barrier 1: everyone done READING Bs (no counter drain) ----
    __builtin_amdgcn_s_barrier();
    __builtin_amdgcn_sched_barrier(0);
    if (t + 1 < NT) {
      writeB(breg);                   // breg uses force compiler vmcnt waits
      asm volatile("s_waitcnt vmcnt(0) lgkmcnt(0)" ::: "memory");  // A in LDS, Bs written
      __builtin_amdgcn_sched_barrier(0);
      __builtin_amdgcn_s_barrier();   // publish As[nxt] + Bs(t+1)
      __builtin_amdgcn_sched_barrier(0);
      cur ^= 1;
    }
  }

  // ---- epilogue ----
  // C layout (m89): col = lane&15, row = (lane>>4)*4 + j
  #pragma unroll
  for (int m = 0; m < 4; ++m) {
    #pragma unroll
    for (int n = 0; n < 4; ++n) {
      int rowb = wr * 64 + m * 16 + ((lane >> 4) << 2);
      int col  = n0 + wc * 64 + n * 16 + (lane & 15);
      #pragma unroll
      for (int jj = 0; jj < 4; ++jj) {
        float xv = acc[m][n][jj];
        if (GELU) {
          // tanh-form GELU: y/(1+exp(-2u)), u = 0.79788456(y + 0.044715 y^3)
          float y = fminf(fmaxf(xv, -8.f), 8.f);
          float u = 0.7978845608f * (y + 0.044715f * y * y * y);
          float t2 = __expf(-2.f * u);
          float g = __fdividef(y, 1.f + t2);
          actout[(size_t)(row0 + rowb + jj) * N + col] = f2bf(g);
        } else {
          redout[(size_t)(row0 + rowb + jj) * N + col] = xv;
        }
      }
    }
  }
}

// out[t][:] = h2[sidx[2t]][:] + h2[sidx[2t+1]][:]   (fully overwrites d_out)
__global__ void k_reduce(const float* __restrict__ h2, const int* __restrict__ sidx,
                         float* __restrict__ out) {
  int t = blockIdx.x;
  int c = threadIdx.x;                        // 256 threads x f4 = 1024 floats
  const f4* r0 = (const f4*)(h2 + (size_t)sidx[2 * t] * HD);
  const f4* r1 = (const f4*)(h2 + (size_t)sidx[2 * t + 1] * HD);
  ((f4*)(out + (size_t)t * HD))[c] = r0[c] + r1[c];
}

extern "C" void kernel_launch(void* const* d_in, const int* in_sizes, int n_in,
                              void* d_out, int out_size, void* d_ws, size_t ws_size,
                              hipStream_t stream) {
  const float* inp  = (const float*)d_in[0];
  const float* w1   = (const float*)d_in[1];
  const float* w2   = (const float*)d_in[2];
  const int*   sidx = (const int*)d_in[3];
  float* out = (float*)d_out;

  char* ws   = (char*)d_ws;
  int*   s2t = (int*)ws;                                          // 64 KB
  u16*   X   = (u16*)(ws + (1 << 20));                            // 32 MB bf16 [MTOT][HD]
  u16*   act = (u16*)(ws + (1 << 20) + (32u << 20));              // 64 MB bf16 [MTOT][FFND]
  float* h2  = (float*)(ws + (1 << 20) + (96u << 20));            // 64 MB f32 [MTOT][HD]

  k_build_s2t<<<MTOT / 256, 256, 0, stream>>>(sidx, s2t);
  k_gather_x<<<(MTOT * (HD / 8)) / 256, 256, 0, stream>>>(inp, s2t, X);
  moe_gemm<HD, FFND, true><<<dim3(FFND / 128, NE), 512, 0, stream>>>(X, w1, act, nullptr);
  moe_gemm<FFND, HD, false><<<dim3(HD / 128, NE), 512, 0, stream>>>(act, w2, nullptr, h2);
  k_reduce<<<NTOK, 256, 0, stream>>>(h2, sidx, out);
}